// Round 4
// baseline (2819.602 us; speedup 1.0000x reference)
//
#include <hip/hip_runtime.h>
#include <hip/hip_bf16.h>
#include <cstddef>
#include <cstdint>

#define NN 2048      // nodes (M and K of the big GEMMs)
#define CIN 2
#define HH 32        // hidden
#define EMB 16
#define HOR 12
#define BB 32        // batch
#define TT 16        // time steps
#define GC 128       // 4*HH gate channels
#define XCOLS 1024   // B*T*C
#define HCOLS 1024   // B*H  (GEMM N dim)
#define KSPLIT 2
#define KS (NN / KSPLIT)          // 1024 per k-slice
#define NIT (KS / 32)             // 32 K-iterations
#define CSZ ((size_t)NN * HCOLS)  // one partial C: 2M floats
#define LDSBUF 24576

typedef __attribute__((ext_vector_type(8))) short bf16x8;
typedef __attribute__((ext_vector_type(4))) float f32x4;
typedef unsigned short u16;

__device__ inline u16 f2bf(float f) {
    __hip_bfloat16 h = __float2bfloat16(f);
    return *reinterpret_cast<u16*>(&h);
}
__device__ inline float bf2f(u16 u) {
    __hip_bfloat16 h = *reinterpret_cast<__hip_bfloat16*>(&u);
    return __bfloat162float(h);
}
__device__ inline void split_bf(float v, u16& hi, u16& lo) {
    hi = f2bf(v);
    lo = f2bf(v - bf2f(hi));
}

// ---------------------------------------------------------------------------
// Kernel 1: A = softmax(relu(E1 @ E2^T)) row-wise -> bf16 hi/lo splits.
// ---------------------------------------------------------------------------
__global__ __launch_bounds__(256) void adj_softmax(const float* __restrict__ E1,
                                                   const float* __restrict__ E2,
                                                   u16* __restrict__ Ahi,
                                                   u16* __restrict__ Alo) {
    const int i = blockIdx.x;
    __shared__ float red[256];
    float e1[EMB];
#pragma unroll
    for (int k = 0; k < EMB; ++k) e1[k] = E1[i * EMB + k];

    float s[8];
    float mx = -1e30f;
#pragma unroll
    for (int q = 0; q < 8; ++q) {
        const int j = q * 256 + threadIdx.x;
        float d = 0.f;
#pragma unroll
        for (int k = 0; k < EMB; ++k) d += e1[k] * E2[j * EMB + k];
        d = fmaxf(d, 0.0f);
        s[q] = d;
        mx = fmaxf(mx, d);
    }
    red[threadIdx.x] = mx;
    __syncthreads();
    for (int off = 128; off > 0; off >>= 1) {
        if (threadIdx.x < off) red[threadIdx.x] = fmaxf(red[threadIdx.x], red[threadIdx.x + off]);
        __syncthreads();
    }
    mx = red[0];
    __syncthreads();

    float sum = 0.f;
#pragma unroll
    for (int q = 0; q < 8; ++q) { s[q] = expf(s[q] - mx); sum += s[q]; }
    red[threadIdx.x] = sum;
    __syncthreads();
    for (int off = 128; off > 0; off >>= 1) {
        if (threadIdx.x < off) red[threadIdx.x] += red[threadIdx.x + off];
        __syncthreads();
    }
    const float inv = 1.0f / red[0];
#pragma unroll
    for (int q = 0; q < 8; ++q) {
        const float v = s[q] * inv;
        u16 hi, lo; split_bf(v, hi, lo);
        const size_t off = (size_t)i * NN + q * 256 + threadIdx.x;
        Ahi[off] = hi; Alo[off] = lo;
    }
}

// ---------------------------------------------------------------------------
// Kernel 2: XT[col][node] bf16 hi/lo, col = (b*T+t)*C + c
// ---------------------------------------------------------------------------
__global__ __launch_bounds__(256) void transpose_x(const float* __restrict__ x,
                                                   u16* __restrict__ XTh,
                                                   u16* __restrict__ XTl) {
    const int idx = blockIdx.x * 256 + threadIdx.x;
    const int col = idx >> 11;
    const int j   = idx & (NN - 1);
    const int bt  = col >> 1;
    const int c   = col & 1;
    const float v = x[((size_t)bt * NN + j) * CIN + c];
    u16 hi, lo; split_bf(v, hi, lo);
    XTh[idx] = hi; XTl[idx] = lo;
}

// ---------------------------------------------------------------------------
// Kernel 3: split-K bf16x3 MFMA GEMM, software-pipelined.
// Cp[z][2048][1024] = A[.][z-slice] * B[z-slice][.]   (z = blockIdx.z)
// 128x64 tile, BK=32, 256 threads (4 waves, each 64x32 of 16x16x32 MFMA).
// Pipeline: glb->VGPR prefetch (tile k+1) | ds_write (tile k) | 1 barrier/iter
// LDS double buffer 2 x 24KB: A hi/lo [kq4][row128][16B], B hi/lo [kq4][row64][16B]
// ---------------------------------------------------------------------------
__global__ __launch_bounds__(256, 2) void gemm3p(const u16* __restrict__ Ahi_,
                                                 const u16* __restrict__ Alo_,
                                                 const u16* __restrict__ Bhi_,
                                                 const u16* __restrict__ Blo_,
                                                 float* __restrict__ Cp) {
    __shared__ char smem[2 * LDSBUF];
    const int tid  = threadIdx.x;
    const int w    = tid >> 6;
    const int lane = tid & 63;
    const int m0 = blockIdx.y * 128;
    const int n0 = blockIdx.x * 64;
    const int k0 = blockIdx.z * KS;

    // 24 chunks of 1KB per tile; wave w owns chunks w*6 .. w*6+5
    const u16* gp[6];
    int        ldst[6];
#pragma unroll
    for (int j = 0; j < 6; ++j) {
        const int ch = w * 6 + j;
        if (ch < 16) {             // A: s(2) x kq(4) x half(2)
            const int s    = ch >> 3;
            const int kq   = (ch >> 1) & 3;
            const int half = ch & 1;
            const u16* base = s ? Alo_ : Ahi_;
            gp[j]   = base + (size_t)(m0 + half * 64 + lane) * NN + k0 + kq * 8;
            ldst[j] = s * 8192 + kq * 2048 + half * 1024 + lane * 16;
        } else {                   // B: s(2) x kq(4)
            const int c2 = ch - 16;
            const int s  = c2 >> 2;
            const int kq = c2 & 3;
            const u16* base = s ? Blo_ : Bhi_;
            gp[j]   = base + (size_t)(n0 + lane) * NN + k0 + kq * 8;
            ldst[j] = 16384 + s * 4096 + kq * 1024 + lane * 16;
        }
    }

    const int q  = lane >> 4;
    const int mr = lane & 15;
    const int wr = (w >> 1) * 64;
    const int wc = (w & 1) * 32;
    int aoff[4][2], boff[2][2];
#pragma unroll
    for (int i = 0; i < 4; ++i)
#pragma unroll
        for (int s = 0; s < 2; ++s)
            aoff[i][s] = s * 8192 + q * 2048 + (wr + i * 16 + mr) * 16;
#pragma unroll
    for (int j = 0; j < 2; ++j)
#pragma unroll
        for (int s = 0; s < 2; ++s)
            boff[j][s] = 16384 + s * 4096 + q * 1024 + (wc + j * 16 + mr) * 16;

    f32x4 acc[4][2];
#pragma unroll
    for (int i = 0; i < 4; ++i)
#pragma unroll
        for (int j = 0; j < 2; ++j) acc[i][j] = (f32x4)(0.0f);

    uint4 Ra[6], Rb[6];

    auto load = [&](uint4* R) {
#pragma unroll
        for (int j = 0; j < 6; ++j) {
            R[j] = *reinterpret_cast<const uint4*>(gp[j]);
            gp[j] += 32;
        }
    };
    auto store_lds = [&](const uint4* R, int buf) {
        char* sb = smem + buf * LDSBUF;
#pragma unroll
        for (int j = 0; j < 6; ++j)
            *reinterpret_cast<uint4*>(sb + ldst[j]) = R[j];
    };
    auto compute = [&](int buf) {
        const char* sb = smem + buf * LDSBUF;
        bf16x8 fa[4][2], fb[2][2];
#pragma unroll
        for (int i = 0; i < 4; ++i)
#pragma unroll
            for (int s = 0; s < 2; ++s)
                fa[i][s] = *reinterpret_cast<const bf16x8*>(sb + aoff[i][s]);
#pragma unroll
        for (int j = 0; j < 2; ++j)
#pragma unroll
            for (int s = 0; s < 2; ++s)
                fb[j][s] = *reinterpret_cast<const bf16x8*>(sb + boff[j][s]);
#pragma unroll
        for (int i = 0; i < 4; ++i)
#pragma unroll
            for (int j = 0; j < 2; ++j) {
                acc[i][j] = __builtin_amdgcn_mfma_f32_16x16x32_bf16(fa[i][0], fb[j][0], acc[i][j], 0, 0, 0);
                acc[i][j] = __builtin_amdgcn_mfma_f32_16x16x32_bf16(fa[i][0], fb[j][1], acc[i][j], 0, 0, 0);
                acc[i][j] = __builtin_amdgcn_mfma_f32_16x16x32_bf16(fa[i][1], fb[j][0], acc[i][j], 0, 0, 0);
            }
    };

    load(Ra);                    // tile 0 in flight
#pragma unroll 1
    for (int it2 = 0; it2 < NIT; it2 += 2) {
        // even iter: consume Ra, prefetch Rb
        store_lds(Ra, 0);                       // vmcnt wait on Ra happens here
        load(Rb);                               // tile it2+1 (always valid: it2+1 <= NIT-1)
        __syncthreads();
        compute(0);
        // odd iter: consume Rb, prefetch Ra
        store_lds(Rb, 1);
        if (it2 + 2 < NIT) load(Ra);            // tile it2+2
        __syncthreads();
        compute(1);
    }

    float* Cs = Cp + (size_t)blockIdx.z * CSZ;
#pragma unroll
    for (int i = 0; i < 4; ++i)
#pragma unroll
        for (int j = 0; j < 2; ++j)
#pragma unroll
            for (int r = 0; r < 4; ++r) {
                const int row = m0 + wr + i * 16 + q * 4 + r;
                const int col = n0 + wc + j * 16 + mr;
                Cs[(size_t)row * HCOLS + col] = acc[i][j][r];
            }
}

// ---------------------------------------------------------------------------
// Kernel 3b: AX = sum of KSPLIT k-slice partials (one-time, for the x path)
// ---------------------------------------------------------------------------
__global__ __launch_bounds__(256) void reduce_ax(const float* __restrict__ P,
                                                 float* __restrict__ AX) {
    const size_t idx = (size_t)blockIdx.x * 256 + threadIdx.x;  // over CSZ/4 float4
    const float4* P4 = (const float4*)P;
    const size_t q = CSZ / 4;
    float4 a = P4[idx], b = P4[idx + q];
    float4 r;
    r.x = a.x + b.x;
    r.y = a.y + b.y;
    r.z = a.z + b.z;
    r.w = a.w + b.w;
    ((float4*)AX)[idx] = r;
}

// ---------------------------------------------------------------------------
// Kernel 3c: weight prep. Whr[k][h][g] = Wh[k][g*32+h]; Wxr[c][h][g]; bfold.
// ---------------------------------------------------------------------------
__global__ __launch_bounds__(256) void prep_weights(const float* __restrict__ Wx,
                                                    const float* __restrict__ bx,
                                                    const float* __restrict__ Wh,
                                                    const float* __restrict__ bh,
                                                    float* __restrict__ Whr,
                                                    float* __restrict__ Wxr,
                                                    float* __restrict__ bfold) {
    const int tid = threadIdx.x;
#pragma unroll
    for (int r = 0; r < 16; ++r) {
        const int idx = tid * 16 + r;           // 4096
        const int k = idx >> 7, rem = idx & 127;
        const int h = rem >> 2, g = rem & 3;
        Whr[idx] = Wh[k * GC + g * HH + h];
    }
    {
        const int idx = tid;                    // 256
        const int c = idx >> 7, rem = idx & 127;
        const int h = rem >> 2, g = rem & 3;
        Wxr[idx] = Wx[c * GC + g * HH + h];
    }
    if (tid < 128) {
        const int h = tid >> 2, g = tid & 3;
        bfold[tid] = bx[g * HH + h] + bh[g * HH + h];
    }
}

// ---------------------------------------------------------------------------
// Kernel 4: gates + cell update, 64 nodes x 1 batch per block.
// Reads KSPLIT k-slice partials of Ah inline. Whr broadcast from LDS.
// ---------------------------------------------------------------------------
__global__ __launch_bounds__(256) void gate_update(const float* __restrict__ AX,   // [NN][XCOLS]
                                                   const float* __restrict__ Ahp,  // KSPLIT x [NN][HCOLS]
                                                   const float* __restrict__ Whr,  // [32][32][4]
                                                   const float* __restrict__ Wxr,  // [2][32][4]
                                                   const float* __restrict__ bfold,// [32][4]
                                                   float* __restrict__ c,
                                                   float* __restrict__ h32,
                                                   u16* __restrict__ hTh,          // [HCOLS][NN]
                                                   u16* __restrict__ hTl,
                                                   int t, int first) {
    const int n0 = blockIdx.x * 64;
    const int b  = blockIdx.y;
    const int tid = threadIdx.x;
    __shared__ float whr[4096];
    __shared__ float wxr[256];
    __shared__ float bfl[128];
    __shared__ float ah_s[64][33];
    __shared__ float axs[2][64];

#pragma unroll
    for (int r = 0; r < 4; ++r)
        *(float4*)&whr[(tid * 4 + r * 1024)] = *(const float4*)&Whr[(tid * 4 + r * 1024)];
    if (tid < 64)  *(float4*)&wxr[tid * 4] = *(const float4*)&Wxr[tid * 4];
    if (tid < 32)  *(float4*)&bfl[tid * 4] = *(const float4*)&bfold[tid * 4];

    if (!first) {
        const int nl = tid >> 2;
        const int kq = (tid & 3) * 8;
        float4 a0 = make_float4(0, 0, 0, 0), a1 = make_float4(0, 0, 0, 0);
#pragma unroll
        for (int s = 0; s < KSPLIT; ++s) {
            const float* src = Ahp + s * CSZ + (size_t)(n0 + nl) * HCOLS + b * HH + kq;
            const float4 v0 = *(const float4*)src;
            const float4 v1 = *(const float4*)(src + 4);
            a0.x += v0.x; a0.y += v0.y; a0.z += v0.z; a0.w += v0.w;
            a1.x += v1.x; a1.y += v1.y; a1.z += v1.z; a1.w += v1.w;
        }
        ah_s[nl][kq + 0] = a0.x; ah_s[nl][kq + 1] = a0.y;
        ah_s[nl][kq + 2] = a0.z; ah_s[nl][kq + 3] = a0.w;
        ah_s[nl][kq + 4] = a1.x; ah_s[nl][kq + 5] = a1.y;
        ah_s[nl][kq + 6] = a1.z; ah_s[nl][kq + 7] = a1.w;
    }
    if (tid < 128) {
        const int which = tid >> 6, nl = tid & 63;
        axs[which][nl] = AX[(size_t)(n0 + nl) * XCOLS + (b * TT + t) * CIN + which];
    }
    __syncthreads();

    const int nl = tid & 63;
    const int hq = tid >> 6;     // handles h-units hq*8 .. hq*8+7
    const float ax0 = axs[0][nl], ax1 = axs[1][nl];

    float acc[8][4];
#pragma unroll
    for (int u = 0; u < 8; ++u) {
        const int h = hq * 8 + u;
#pragma unroll
        for (int g = 0; g < 4; ++g)
            acc[u][g] = bfl[h * 4 + g] + ax0 * wxr[h * 4 + g] + ax1 * wxr[128 + h * 4 + g];
    }
    if (!first) {
        float ah_r[HH];
#pragma unroll
        for (int k = 0; k < HH; ++k) ah_r[k] = ah_s[nl][k];
#pragma unroll 4
        for (int k = 0; k < HH; ++k) {
            const float a = ah_r[k];
#pragma unroll
            for (int u = 0; u < 8; ++u) {
                const float* wp = &whr[(k * HH + hq * 8 + u) * 4];
                acc[u][0] += a * wp[0];
                acc[u][1] += a * wp[1];
                acc[u][2] += a * wp[2];
                acc[u][3] += a * wp[3];
            }
        }
    }

    float cn[8], hn[8];
    const size_t off = (size_t)(n0 + nl) * HCOLS + b * HH + hq * 8;
    float4 c0o = make_float4(0, 0, 0, 0), c1o = make_float4(0, 0, 0, 0);
    if (!first) { c0o = *(const float4*)(c + off); c1o = *(const float4*)(c + off + 4); }
    const float cold[8] = {c0o.x, c0o.y, c0o.z, c0o.w, c1o.x, c1o.y, c1o.z, c1o.w};
#pragma unroll
    for (int u = 0; u < 8; ++u) {
        const float i_ = 1.0f / (1.0f + expf(-acc[u][0]));
        const float f_ = 1.0f / (1.0f + expf(-acc[u][1]));
        const float o_ = 1.0f / (1.0f + expf(-acc[u][2]));
        const float g_ = tanhf(acc[u][3]);
        const float c_t = f_ * cold[u] + i_ * g_;
        cn[u] = c_t;
        hn[u] = o_ * tanhf(c_t);
    }
    *(float4*)(c + off)       = make_float4(cn[0], cn[1], cn[2], cn[3]);
    *(float4*)(c + off + 4)   = make_float4(cn[4], cn[5], cn[6], cn[7]);
    *(float4*)(h32 + off)     = make_float4(hn[0], hn[1], hn[2], hn[3]);
    *(float4*)(h32 + off + 4) = make_float4(hn[4], hn[5], hn[6], hn[7]);
#pragma unroll
    for (int u = 0; u < 8; ++u) {
        u16 hh, hl; split_bf(hn[u], hh, hl);
        const size_t toff = (size_t)(b * HH + hq * 8 + u) * NN + n0 + nl;
        hTh[toff] = hh; hTl[toff] = hl;
    }
}

// ---------------------------------------------------------------------------
// Kernel 5: out[b][th][n] = bp[th] + sum_k h[n][b*H+k] * Wp[k][th]
// ---------------------------------------------------------------------------
__global__ __launch_bounds__(256) void head_kernel(const float* __restrict__ h,
                                                   const float* __restrict__ Wp,
                                                   const float* __restrict__ bp,
                                                   float* __restrict__ out) {
    const int idx = blockIdx.x * 256 + threadIdx.x;
    const int b = idx >> 11;
    const int n = idx & (NN - 1);
    float hv[HH];
    const float* hp = h + (size_t)n * HCOLS + b * HH;
#pragma unroll
    for (int k = 0; k < HH; ++k) hv[k] = hp[k];
#pragma unroll
    for (int th = 0; th < HOR; ++th) {
        float acc = bp[th];
#pragma unroll
        for (int k = 0; k < HH; ++k) acc += hv[k] * Wp[k * HOR + th];
        out[((size_t)b * HOR + th) * NN + n] = acc;
    }
}

// ---------------------------------------------------------------------------
extern "C" void kernel_launch(void* const* d_in, const int* in_sizes, int n_in,
                              void* d_out, int out_size, void* d_ws, size_t ws_size,
                              hipStream_t stream) {
    const float* x  = (const float*)d_in[0];
    const float* E1 = (const float*)d_in[1];
    const float* E2 = (const float*)d_in[2];
    const float* Wx = (const float*)d_in[3];
    const float* bx = (const float*)d_in[4];
    const float* Wh = (const float*)d_in[5];
    const float* bh = (const float*)d_in[6];
    const float* Wp = (const float*)d_in[7];
    const float* bp = (const float*)d_in[8];

    char* ws = (char*)d_ws;
    u16*   A_hi = (u16*)(ws);                         //  8 MB
    u16*   A_lo = (u16*)(ws + (8ull  << 20));         //  8 MB
    u16*   XTh  = (u16*)(ws + (16ull << 20));         //  4 MB (reused as hTh)
    u16*   XTl  = (u16*)(ws + (20ull << 20));         //  4 MB (reused as hTl)
    float* P    = (float*)(ws + (24ull << 20));       // 16 MB (2 k-slice partials)
    float* AX   = (float*)(ws + (56ull << 20));       //  8 MB
    float* cst  = (float*)(ws + (64ull << 20));       //  8 MB
    float* h32  = (float*)(ws + (72ull << 20));       //  8 MB
    float* Whr  = (float*)(ws + (80ull << 20));       // 16 KB
    float* Wxr  = (float*)(ws + (80ull << 20) + 65536);
    float* bfold= (float*)(ws + (80ull << 20) + 131072);
    u16*   hTh  = XTh;
    u16*   hTl  = XTl;

    adj_softmax<<<NN, 256, 0, stream>>>(E1, E2, A_hi, A_lo);
    transpose_x<<<(XCOLS * NN) / 256, 256, 0, stream>>>(x, XTh, XTl);
    prep_weights<<<1, 256, 0, stream>>>(Wx, bx, Wh, bh, Whr, Wxr, bfold);

    dim3 gg(HCOLS / 64, NN / 128, KSPLIT);   // 16 x 16 x 2 = 512 blocks
    gemm3p<<<gg, 256, 0, stream>>>(A_hi, A_lo, XTh, XTl, P);
    reduce_ax<<<(int)(CSZ / 4 / 256), 256, 0, stream>>>(P, AX);

    for (int t = 0; t < TT; ++t) {
        if (t > 0)
            gemm3p<<<gg, 256, 0, stream>>>(A_hi, A_lo, hTh, hTl, P);
        gate_update<<<dim3(NN / 64, BB), 256, 0, stream>>>(AX, P, Whr, Wxr, bfold,
                                                           cst, h32, hTh, hTl, t, t == 0 ? 1 : 0);
    }

    head_kernel<<<(BB * NN) / 256, 256, 0, stream>>>(h32, Wp, bp, (float*)d_out);
}

// Round 5
// 1478.259 us; speedup vs baseline: 1.9074x; 1.9074x over previous
//
#include <hip/hip_runtime.h>
#include <hip/hip_bf16.h>
#include <cstddef>
#include <cstdint>

#define NN 2048      // nodes (M and K of the big GEMMs)
#define CIN 2
#define HH 32        // hidden
#define EMB 16
#define HOR 12
#define BB 32        // batch
#define TT 16        // time steps
#define GC 128       // 4*HH gate channels
#define XCOLS 1024   // B*T*C
#define HCOLS 1024   // B*H  (GEMM N dim)
#define KSPLIT 2
#define KS (NN / KSPLIT)          // 1024 per k-slice
#define NIT (KS / 32)             // 32 K-iterations
#define CSZ ((size_t)NN * HCOLS)  // one partial C: 2M floats
#define LDSBUF 24576

typedef __attribute__((ext_vector_type(8))) short bf16x8;
typedef __attribute__((ext_vector_type(4))) float f32x4;
typedef unsigned short u16;

__device__ inline u16 f2bf(float f) {
    __hip_bfloat16 h = __float2bfloat16(f);
    return *reinterpret_cast<u16*>(&h);
}
__device__ inline float bf2f(u16 u) {
    __hip_bfloat16 h = *reinterpret_cast<__hip_bfloat16*>(&u);
    return __bfloat162float(h);
}
__device__ inline void split_bf(float v, u16& hi, u16& lo) {
    hi = f2bf(v);
    lo = f2bf(v - bf2f(hi));
}

// ---------------------------------------------------------------------------
// Kernel 1: A = softmax(relu(E1 @ E2^T)) row-wise -> bf16 hi/lo splits.
// ---------------------------------------------------------------------------
__global__ __launch_bounds__(256) void adj_softmax(const float* __restrict__ E1,
                                                   const float* __restrict__ E2,
                                                   u16* __restrict__ Ahi,
                                                   u16* __restrict__ Alo) {
    const int i = blockIdx.x;
    __shared__ float red[256];
    float e1[EMB];
#pragma unroll
    for (int k = 0; k < EMB; ++k) e1[k] = E1[i * EMB + k];

    float s[8];
    float mx = -1e30f;
#pragma unroll
    for (int q = 0; q < 8; ++q) {
        const int j = q * 256 + threadIdx.x;
        float d = 0.f;
#pragma unroll
        for (int k = 0; k < EMB; ++k) d += e1[k] * E2[j * EMB + k];
        d = fmaxf(d, 0.0f);
        s[q] = d;
        mx = fmaxf(mx, d);
    }
    red[threadIdx.x] = mx;
    __syncthreads();
    for (int off = 128; off > 0; off >>= 1) {
        if (threadIdx.x < off) red[threadIdx.x] = fmaxf(red[threadIdx.x], red[threadIdx.x + off]);
        __syncthreads();
    }
    mx = red[0];
    __syncthreads();

    float sum = 0.f;
#pragma unroll
    for (int q = 0; q < 8; ++q) { s[q] = expf(s[q] - mx); sum += s[q]; }
    red[threadIdx.x] = sum;
    __syncthreads();
    for (int off = 128; off > 0; off >>= 1) {
        if (threadIdx.x < off) red[threadIdx.x] += red[threadIdx.x + off];
        __syncthreads();
    }
    const float inv = 1.0f / red[0];
#pragma unroll
    for (int q = 0; q < 8; ++q) {
        const float v = s[q] * inv;
        u16 hi, lo; split_bf(v, hi, lo);
        const size_t off = (size_t)i * NN + q * 256 + threadIdx.x;
        Ahi[off] = hi; Alo[off] = lo;
    }
}

// ---------------------------------------------------------------------------
// Kernel 2: XT[col][node] bf16 hi/lo, col = (b*T+t)*C + c
// ---------------------------------------------------------------------------
__global__ __launch_bounds__(256) void transpose_x(const float* __restrict__ x,
                                                   u16* __restrict__ XTh,
                                                   u16* __restrict__ XTl) {
    const int idx = blockIdx.x * 256 + threadIdx.x;
    const int col = idx >> 11;
    const int j   = idx & (NN - 1);
    const int bt  = col >> 1;
    const int c   = col & 1;
    const float v = x[((size_t)bt * NN + j) * CIN + c];
    u16 hi, lo; split_bf(v, hi, lo);
    XTh[idx] = hi; XTl[idx] = lo;
}

// ---------------------------------------------------------------------------
// Kernel 3: split-K bf16x3 MFMA GEMM, software-pipelined, spill-proof.
// Cp[z][2048][1024] = A[.][z-slice] * B[z-slice][.]   (z = blockIdx.z)
// 128x64 tile, BK=32, 256 threads (4 waves, each 64x32 of 16x16x32 MFMA).
// Pipeline: glb->VGPR prefetch depth 2 | ds_write tile k | 1 barrier/iter.
// All staging state in named scalars (macros) - NO arrays through pointers.
// ---------------------------------------------------------------------------
__global__ __launch_bounds__(256, 2) void gemm3p(const u16* __restrict__ Ahi_,
                                                 const u16* __restrict__ Alo_,
                                                 const u16* __restrict__ Bhi_,
                                                 const u16* __restrict__ Blo_,
                                                 float* __restrict__ Cp) {
    __shared__ char smem[2 * LDSBUF];
    const int tid  = threadIdx.x;
    const int w    = tid >> 6;
    const int lane = tid & 63;
    const int m0 = blockIdx.y * 128;
    const int n0 = blockIdx.x * 64;
    const int k0 = blockIdx.z * KS;

    // 24 chunks of 1KB per tile; wave w owns chunks w*6 .. w*6+5
    const u16 *gp0, *gp1, *gp2, *gp3, *gp4, *gp5;
    int ld0, ld1, ld2, ld3, ld4, ld5;

#define SETUP(J, GP, LD) do {                                                  \
        const int ch = w * 6 + (J);                                            \
        if (ch < 16) {                                                         \
            const int s = ch >> 3, kq = (ch >> 1) & 3, half = ch & 1;          \
            const u16* base = s ? Alo_ : Ahi_;                                 \
            GP = base + (size_t)(m0 + half * 64 + lane) * NN + k0 + kq * 8;    \
            LD = s * 8192 + kq * 2048 + half * 1024 + lane * 16;               \
        } else {                                                               \
            const int c2 = ch - 16, s = c2 >> 2, kq = c2 & 3;                  \
            const u16* base = s ? Blo_ : Bhi_;                                 \
            GP = base + (size_t)(n0 + lane) * NN + k0 + kq * 8;                \
            LD = 16384 + s * 4096 + kq * 1024 + lane * 16;                     \
        }                                                                      \
    } while (0)
    SETUP(0, gp0, ld0); SETUP(1, gp1, ld1); SETUP(2, gp2, ld2);
    SETUP(3, gp3, ld3); SETUP(4, gp4, ld4); SETUP(5, gp5, ld5);
#undef SETUP

    const int q  = lane >> 4;
    const int mr = lane & 15;
    const int wr = (w >> 1) * 64;
    const int wc = (w & 1) * 32;
    int aoff[4][2], boff[2][2];
#pragma unroll
    for (int i = 0; i < 4; ++i)
#pragma unroll
        for (int s = 0; s < 2; ++s)
            aoff[i][s] = s * 8192 + q * 2048 + (wr + i * 16 + mr) * 16;
#pragma unroll
    for (int j = 0; j < 2; ++j)
#pragma unroll
        for (int s = 0; s < 2; ++s)
            boff[j][s] = 16384 + s * 4096 + q * 1024 + (wc + j * 16 + mr) * 16;

    f32x4 acc[4][2];
#pragma unroll
    for (int i = 0; i < 4; ++i)
#pragma unroll
        for (int j = 0; j < 2; ++j) acc[i][j] = (f32x4)(0.0f);

    uint4 Ra0, Ra1, Ra2, Ra3, Ra4, Ra5;
    uint4 Rb0, Rb1, Rb2, Rb3, Rb4, Rb5;

#define LOADR(R)                                                               \
    R##0 = *(const uint4*)gp0; gp0 += 32;                                      \
    R##1 = *(const uint4*)gp1; gp1 += 32;                                      \
    R##2 = *(const uint4*)gp2; gp2 += 32;                                      \
    R##3 = *(const uint4*)gp3; gp3 += 32;                                      \
    R##4 = *(const uint4*)gp4; gp4 += 32;                                      \
    R##5 = *(const uint4*)gp5; gp5 += 32;

#define STORER(R, SB)                                                          \
    *(uint4*)((SB) + ld0) = R##0;                                              \
    *(uint4*)((SB) + ld1) = R##1;                                              \
    *(uint4*)((SB) + ld2) = R##2;                                              \
    *(uint4*)((SB) + ld3) = R##3;                                              \
    *(uint4*)((SB) + ld4) = R##4;                                              \
    *(uint4*)((SB) + ld5) = R##5;

#define COMPUTE(BUF) do {                                                      \
        const char* sb = smem + (BUF) * LDSBUF;                                \
        bf16x8 fa[4][2], fb[2][2];                                             \
        _Pragma("unroll") for (int i = 0; i < 4; ++i)                          \
        _Pragma("unroll") for (int s = 0; s < 2; ++s)                          \
            fa[i][s] = *reinterpret_cast<const bf16x8*>(sb + aoff[i][s]);      \
        _Pragma("unroll") for (int j = 0; j < 2; ++j)                          \
        _Pragma("unroll") for (int s = 0; s < 2; ++s)                          \
            fb[j][s] = *reinterpret_cast<const bf16x8*>(sb + boff[j][s]);      \
        _Pragma("unroll") for (int i = 0; i < 4; ++i)                          \
        _Pragma("unroll") for (int j = 0; j < 2; ++j) {                        \
            acc[i][j] = __builtin_amdgcn_mfma_f32_16x16x32_bf16(fa[i][0], fb[j][0], acc[i][j], 0, 0, 0); \
            acc[i][j] = __builtin_amdgcn_mfma_f32_16x16x32_bf16(fa[i][0], fb[j][1], acc[i][j], 0, 0, 0); \
            acc[i][j] = __builtin_amdgcn_mfma_f32_16x16x32_bf16(fa[i][1], fb[j][0], acc[i][j], 0, 0, 0); \
        }                                                                      \
    } while (0)

    LOADR(Ra)        // tile 0 in flight
    LOADR(Rb)        // tile 1 in flight

#pragma unroll 1
    for (int it = 0; it < NIT; it += 2) {
        STORER(Ra, smem)                 // waits vmcnt for Ra (issued 2 iters ago)
        __syncthreads();
        if (it + 2 < NIT) { LOADR(Ra) }  // tile it+2, consumed 2 phases later
        COMPUTE(0);
        STORER(Rb, smem + LDSBUF)
        __syncthreads();
        if (it + 3 < NIT) { LOADR(Rb) }  // tile it+3
        COMPUTE(1);
    }
#undef LOADR
#undef STORER
#undef COMPUTE

    float* Cs = Cp + (size_t)blockIdx.z * CSZ;
#pragma unroll
    for (int i = 0; i < 4; ++i)
#pragma unroll
        for (int j = 0; j < 2; ++j)
#pragma unroll
            for (int r = 0; r < 4; ++r) {
                const int row = m0 + wr + i * 16 + q * 4 + r;
                const int col = n0 + wc + j * 16 + mr;
                Cs[(size_t)row * HCOLS + col] = acc[i][j][r];
            }
}

// ---------------------------------------------------------------------------
// Kernel 3b: AX = sum of KSPLIT k-slice partials (one-time, for the x path)
// ---------------------------------------------------------------------------
__global__ __launch_bounds__(256) void reduce_ax(const float* __restrict__ P,
                                                 float* __restrict__ AX) {
    const size_t idx = (size_t)blockIdx.x * 256 + threadIdx.x;
    const float4* P4 = (const float4*)P;
    const size_t q = CSZ / 4;
    float4 a = P4[idx], b = P4[idx + q];
    float4 r;
    r.x = a.x + b.x;
    r.y = a.y + b.y;
    r.z = a.z + b.z;
    r.w = a.w + b.w;
    ((float4*)AX)[idx] = r;
}

// ---------------------------------------------------------------------------
// Kernel 3c: weight prep. Whr[k][h][g] = Wh[k][g*32+h]; Wxr[c][h][g]; bfold.
// ---------------------------------------------------------------------------
__global__ __launch_bounds__(256) void prep_weights(const float* __restrict__ Wx,
                                                    const float* __restrict__ bx,
                                                    const float* __restrict__ Wh,
                                                    const float* __restrict__ bh,
                                                    float* __restrict__ Whr,
                                                    float* __restrict__ Wxr,
                                                    float* __restrict__ bfold) {
    const int tid = threadIdx.x;
#pragma unroll
    for (int r = 0; r < 16; ++r) {
        const int idx = tid * 16 + r;           // 4096
        const int k = idx >> 7, rem = idx & 127;
        const int h = rem >> 2, g = rem & 3;
        Whr[idx] = Wh[k * GC + g * HH + h];
    }
    {
        const int idx = tid;                    // 256
        const int c = idx >> 7, rem = idx & 127;
        const int h = rem >> 2, g = rem & 3;
        Wxr[idx] = Wx[c * GC + g * HH + h];
    }
    if (tid < 128) {
        const int h = tid >> 2, g = tid & 3;
        bfold[tid] = bx[g * HH + h] + bh[g * HH + h];
    }
}

// ---------------------------------------------------------------------------
// Kernel 4: gates + cell update, 64 nodes x 1 batch per block.
// ---------------------------------------------------------------------------
__global__ __launch_bounds__(256) void gate_update(const float* __restrict__ AX,
                                                   const float* __restrict__ Ahp,
                                                   const float* __restrict__ Whr,
                                                   const float* __restrict__ Wxr,
                                                   const float* __restrict__ bfold,
                                                   float* __restrict__ c,
                                                   float* __restrict__ h32,
                                                   u16* __restrict__ hTh,
                                                   u16* __restrict__ hTl,
                                                   int t, int first) {
    const int n0 = blockIdx.x * 64;
    const int b  = blockIdx.y;
    const int tid = threadIdx.x;
    __shared__ float whr[4096];
    __shared__ float wxr[256];
    __shared__ float bfl[128];
    __shared__ float ah_s[64][33];
    __shared__ float axs[2][64];

#pragma unroll
    for (int r = 0; r < 4; ++r)
        *(float4*)&whr[(tid * 4 + r * 1024)] = *(const float4*)&Whr[(tid * 4 + r * 1024)];
    if (tid < 64)  *(float4*)&wxr[tid * 4] = *(const float4*)&Wxr[tid * 4];
    if (tid < 32)  *(float4*)&bfl[tid * 4] = *(const float4*)&bfold[tid * 4];

    if (!first) {
        const int nl = tid >> 2;
        const int kq = (tid & 3) * 8;
        float4 a0 = make_float4(0, 0, 0, 0), a1 = make_float4(0, 0, 0, 0);
#pragma unroll
        for (int s = 0; s < KSPLIT; ++s) {
            const float* src = Ahp + s * CSZ + (size_t)(n0 + nl) * HCOLS + b * HH + kq;
            const float4 v0 = *(const float4*)src;
            const float4 v1 = *(const float4*)(src + 4);
            a0.x += v0.x; a0.y += v0.y; a0.z += v0.z; a0.w += v0.w;
            a1.x += v1.x; a1.y += v1.y; a1.z += v1.z; a1.w += v1.w;
        }
        ah_s[nl][kq + 0] = a0.x; ah_s[nl][kq + 1] = a0.y;
        ah_s[nl][kq + 2] = a0.z; ah_s[nl][kq + 3] = a0.w;
        ah_s[nl][kq + 4] = a1.x; ah_s[nl][kq + 5] = a1.y;
        ah_s[nl][kq + 6] = a1.z; ah_s[nl][kq + 7] = a1.w;
    }
    if (tid < 128) {
        const int which = tid >> 6, nl = tid & 63;
        axs[which][nl] = AX[(size_t)(n0 + nl) * XCOLS + (b * TT + t) * CIN + which];
    }
    __syncthreads();

    const int nl = tid & 63;
    const int hq = tid >> 6;
    const float ax0 = axs[0][nl], ax1 = axs[1][nl];

    float acc[8][4];
#pragma unroll
    for (int u = 0; u < 8; ++u) {
        const int h = hq * 8 + u;
#pragma unroll
        for (int g = 0; g < 4; ++g)
            acc[u][g] = bfl[h * 4 + g] + ax0 * wxr[h * 4 + g] + ax1 * wxr[128 + h * 4 + g];
    }
    if (!first) {
        float ah_r[HH];
#pragma unroll
        for (int k = 0; k < HH; ++k) ah_r[k] = ah_s[nl][k];
#pragma unroll 4
        for (int k = 0; k < HH; ++k) {
            const float a = ah_r[k];
#pragma unroll
            for (int u = 0; u < 8; ++u) {
                const float* wp = &whr[(k * HH + hq * 8 + u) * 4];
                acc[u][0] += a * wp[0];
                acc[u][1] += a * wp[1];
                acc[u][2] += a * wp[2];
                acc[u][3] += a * wp[3];
            }
        }
    }

    float cn[8], hn[8];
    const size_t off = (size_t)(n0 + nl) * HCOLS + b * HH + hq * 8;
    float4 c0o = make_float4(0, 0, 0, 0), c1o = make_float4(0, 0, 0, 0);
    if (!first) { c0o = *(const float4*)(c + off); c1o = *(const float4*)(c + off + 4); }
    const float cold[8] = {c0o.x, c0o.y, c0o.z, c0o.w, c1o.x, c1o.y, c1o.z, c1o.w};
#pragma unroll
    for (int u = 0; u < 8; ++u) {
        const float i_ = 1.0f / (1.0f + expf(-acc[u][0]));
        const float f_ = 1.0f / (1.0f + expf(-acc[u][1]));
        const float o_ = 1.0f / (1.0f + expf(-acc[u][2]));
        const float g_ = tanhf(acc[u][3]);
        const float c_t = f_ * cold[u] + i_ * g_;
        cn[u] = c_t;
        hn[u] = o_ * tanhf(c_t);
    }
    *(float4*)(c + off)       = make_float4(cn[0], cn[1], cn[2], cn[3]);
    *(float4*)(c + off + 4)   = make_float4(cn[4], cn[5], cn[6], cn[7]);
    *(float4*)(h32 + off)     = make_float4(hn[0], hn[1], hn[2], hn[3]);
    *(float4*)(h32 + off + 4) = make_float4(hn[4], hn[5], hn[6], hn[7]);
#pragma unroll
    for (int u = 0; u < 8; ++u) {
        u16 hh, hl; split_bf(hn[u], hh, hl);
        const size_t toff = (size_t)(b * HH + hq * 8 + u) * NN + n0 + nl;
        hTh[toff] = hh; hTl[toff] = hl;
    }
}

// ---------------------------------------------------------------------------
// Kernel 5: out[b][th][n] = bp[th] + sum_k h[n][b*H+k] * Wp[k][th]
// ---------------------------------------------------------------------------
__global__ __launch_bounds__(256) void head_kernel(const float* __restrict__ h,
                                                   const float* __restrict__ Wp,
                                                   const float* __restrict__ bp,
                                                   float* __restrict__ out) {
    const int idx = blockIdx.x * 256 + threadIdx.x;
    const int b = idx >> 11;
    const int n = idx & (NN - 1);
    float hv[HH];
    const float* hp = h + (size_t)n * HCOLS + b * HH;
#pragma unroll
    for (int k = 0; k < HH; ++k) hv[k] = hp[k];
#pragma unroll
    for (int th = 0; th < HOR; ++th) {
        float acc = bp[th];
#pragma unroll
        for (int k = 0; k < HH; ++k) acc += hv[k] * Wp[k * HOR + th];
        out[((size_t)b * HOR + th) * NN + n] = acc;
    }
}

// ---------------------------------------------------------------------------
extern "C" void kernel_launch(void* const* d_in, const int* in_sizes, int n_in,
                              void* d_out, int out_size, void* d_ws, size_t ws_size,
                              hipStream_t stream) {
    const float* x  = (const float*)d_in[0];
    const float* E1 = (const float*)d_in[1];
    const float* E2 = (const float*)d_in[2];
    const float* Wx = (const float*)d_in[3];
    const float* bx = (const float*)d_in[4];
    const float* Wh = (const float*)d_in[5];
    const float* bh = (const float*)d_in[6];
    const float* Wp = (const float*)d_in[7];
    const float* bp = (const float*)d_in[8];

    char* ws = (char*)d_ws;
    u16*   A_hi = (u16*)(ws);                         //  8 MB
    u16*   A_lo = (u16*)(ws + (8ull  << 20));         //  8 MB
    u16*   XTh  = (u16*)(ws + (16ull << 20));         //  4 MB (reused as hTh)
    u16*   XTl  = (u16*)(ws + (20ull << 20));         //  4 MB (reused as hTl)
    float* P    = (float*)(ws + (24ull << 20));       // 16 MB (2 k-slice partials)
    float* AX   = (float*)(ws + (56ull << 20));       //  8 MB
    float* cst  = (float*)(ws + (64ull << 20));       //  8 MB
    float* h32  = (float*)(ws + (72ull << 20));       //  8 MB
    float* Whr  = (float*)(ws + (80ull << 20));       // 16 KB
    float* Wxr  = (float*)(ws + (80ull << 20) + 65536);
    float* bfold= (float*)(ws + (80ull << 20) + 131072);
    u16*   hTh  = XTh;
    u16*   hTl  = XTl;

    adj_softmax<<<NN, 256, 0, stream>>>(E1, E2, A_hi, A_lo);
    transpose_x<<<(XCOLS * NN) / 256, 256, 0, stream>>>(x, XTh, XTl);
    prep_weights<<<1, 256, 0, stream>>>(Wx, bx, Wh, bh, Whr, Wxr, bfold);

    dim3 gg(HCOLS / 64, NN / 128, KSPLIT);   // 16 x 16 x 2 = 512 blocks
    gemm3p<<<gg, 256, 0, stream>>>(A_hi, A_lo, XTh, XTl, P);
    reduce_ax<<<(int)(CSZ / 4 / 256), 256, 0, stream>>>(P, AX);

    for (int t = 0; t < TT; ++t) {
        if (t > 0)
            gemm3p<<<gg, 256, 0, stream>>>(A_hi, A_lo, hTh, hTl, P);
        gate_update<<<dim3(NN / 64, BB), 256, 0, stream>>>(AX, P, Whr, Wxr, bfold,
                                                           cst, h32, hTh, hTl, t, t == 0 ? 1 : 0);
    }

    head_kernel<<<(BB * NN) / 256, 256, 0, stream>>>(h32, Wp, bp, (float*)d_out);
}